// Round 3
// baseline (708.940 us; speedup 1.0000x reference)
//
#include <hip/hip_runtime.h>
#include <math.h>

#define NV 500000
#define SD 256
#define NS 1000
#define MD 64

// ---------------------------------------------------------------------------
// Kernel 1: tiny prep — moderator sums, per-group scalar constants, zero acc.
// sc layout (floats, at d_ws+16): per group g (stride 8):
//   [0]=v (1/s^2), [1]=sum_m, [2]=sum_m2, [3]=r, [4..7]=three-term table y=0..3
// acc (double) at d_ws+0.
// r = v*sum_m^2/sum_m2 is voxel-independent (mu^2 cancels), so the lgamma
// three-term takes only 4 values per group (y in {0,1,2,3}).
// ---------------------------------------------------------------------------
__global__ void prep_kernel(const float* __restrict__ mod0,
                            const float* __restrict__ mod1,
                            const float* __restrict__ wm,
                            const float* __restrict__ over,
                            double* __restrict__ acc,
                            float* __restrict__ sc) {
    __shared__ float s_wm[MD];
    __shared__ float4 buf[256];
    const int tid = threadIdx.x;
    if (tid < MD) s_wm[tid] = wm[tid];
    __syncthreads();

    float sm0 = 0.f, sq0 = 0.f, sm1 = 0.f, sq1 = 0.f;
    for (int j = tid; j < NS; j += 256) {
        const float* r0 = mod0 + j * MD;
        const float* r1 = mod1 + j * MD;
        float d0 = 0.f, d1 = 0.f;
        #pragma unroll 8
        for (int k = 0; k < MD; ++k) {
            d0 += r0[k] * s_wm[k];
            d1 += r1[k] * s_wm[k];
        }
        float m0 = expf(d0), m1 = expf(d1);
        sm0 += m0; sq0 += m0 * m0;
        sm1 += m1; sq1 += m1 * m1;
    }
    buf[tid] = make_float4(sm0, sq0, sm1, sq1);
    __syncthreads();
    for (int s = 128; s > 0; s >>= 1) {
        if (tid < s) {
            float4 a = buf[tid], b = buf[tid + s];
            buf[tid] = make_float4(a.x + b.x, a.y + b.y, a.z + b.z, a.w + b.w);
        }
        __syncthreads();
    }
    if (tid == 0) {
        const float4 t = buf[0];
        const float summ[2] = { t.x, t.z };
        const float sumq[2] = { t.y, t.w };
        for (int g = 0; g < 2; ++g) {
            const float s_ = over[g];
            const float v  = 1.0f / (s_ * s_);
            const float r  = v * summ[g] * summ[g] / sumq[g];
            sc[g * 8 + 0] = v;
            sc[g * 8 + 1] = summ[g];
            sc[g * 8 + 2] = sumq[g];
            sc[g * 8 + 3] = r;
            const float lgr = lgammaf(r);
            sc[g * 8 + 4] = 0.0f;
            sc[g * 8 + 5] = lgammaf(1.0f + r) - lgammaf(2.0f) - lgr;
            sc[g * 8 + 6] = lgammaf(2.0f + r) - lgammaf(3.0f) - lgr;
            sc[g * 8 + 7] = lgammaf(3.0f + r) - lgammaf(4.0f) - lgr;
        }
        acc[0] = 0.0;
    }
}

// ---------------------------------------------------------------------------
// Kernel 2: main — 4-lanes-per-row dots (16 rows per wave instruction, full
// 64B cache lines), w fragments multicast from LDS (4 distinct addrs/instr,
// conflict-free), 2-level shfl_xor reduce + 1 shfl redistribute per 16
// rows (vs 12 shuffles per row previously). Both groups in one csb pass.
// ---------------------------------------------------------------------------
__global__ void main_kernel(const float* __restrict__ csb,
                            const float* __restrict__ f0,
                            const float* __restrict__ f1,
                            const float* __restrict__ spatial,
                            const float* __restrict__ sc,
                            double* __restrict__ acc) {
    __shared__ float4 s_w0[64];
    __shared__ float4 s_w1[64];
    __shared__ double sred[256];

    const int tid = threadIdx.x;
    if (tid < 64) {
        s_w0[tid] = reinterpret_cast<const float4*>(spatial)[tid];
        s_w1[tid] = reinterpret_cast<const float4*>(spatial + SD)[tid];
    }
    __syncthreads();

    const int lane = tid & 63;
    const int q    = lane & 3;    // quarter-row: cols q*4 + 16*i
    const int rr   = lane >> 2;   // row-in-pass 0..15
    const int wib  = tid >> 6;
    const int gw   = blockIdx.x * (blockDim.x >> 6) + wib;
    const int nw   = gridDim.x * (blockDim.x >> 6);
    const int srcl = (lane & 15) << 2;  // shfl source lane

    // uniform per-group scalars
    const float v0 = sc[0],  smA = sc[1],  sqA = sc[2],  rA = sc[3];
    const float tA1 = sc[5], tA2 = sc[6],  tA3 = sc[7];
    const float v1 = sc[8],  smB = sc[9],  sqB = sc[10], rB = sc[11];
    const float tB1 = sc[13], tB2 = sc[14], tB3 = sc[15];

    double accl = 0.0;
    const int nchunks = (NV + 63) >> 6;
    for (int c = gw; c < nchunks; c += nw) {
        const int base = c << 6;
        float dot0 = 0.f, dot1 = 0.f;  // this lane's voxel (base+lane)
        #pragma unroll
        for (int p = 0; p < 4; ++p) {
            const int row = base + (p << 4) + rr;
            float d0e = 0.f, d0o = 0.f, d1e = 0.f, d1o = 0.f;
            if (row < NV) {  // only last chunk diverges
                const float* rb = csb + (size_t)row * SD + (q << 2);
                #pragma unroll 4
                for (int i = 0; i < 16; ++i) {
                    const float4 a  = *reinterpret_cast<const float4*>(rb + (i << 4));
                    const float4 wa = s_w0[(i << 2) + q];
                    const float4 wb = s_w1[(i << 2) + q];
                    d0e = fmaf(a.x, wa.x, d0e); d0o = fmaf(a.y, wa.y, d0o);
                    d0e = fmaf(a.z, wa.z, d0e); d0o = fmaf(a.w, wa.w, d0o);
                    d1e = fmaf(a.x, wb.x, d1e); d1o = fmaf(a.y, wb.y, d1o);
                    d1e = fmaf(a.z, wb.z, d1e); d1o = fmaf(a.w, wb.w, d1o);
                }
            }
            float d0 = d0e + d0o;
            float d1 = d1e + d1o;
            // reduce across the 4 lanes of each row-group
            d0 += __shfl_xor(d0, 1, 64);
            d0 += __shfl_xor(d0, 2, 64);
            d1 += __shfl_xor(d1, 1, 64);
            d1 += __shfl_xor(d1, 2, 64);
            // redistribute: lane j (j>>4 == p) takes row base+j's dot
            const float g0 = __shfl(d0, srcl, 64);
            const float g1 = __shfl(d1, srcl, 64);
            if ((lane >> 4) == p) { dot0 = g0; dot1 = g1; }
        }
        const int vox = base + lane;
        if (vox < NV) {
            const float y0 = f0[vox];
            const float y1 = f1[vox];
            // group 0 — exact reference formula sequence (f32)
            float mu  = expf(dot0);
            float num = mu * mu * sqA;
            float den = v0 * mu * smA + num;
            float pp  = num / den;
            int   yi  = (int)y0;
            float tt  = (yi == 1) ? tA1 : (yi == 2) ? tA2 : (yi == 3) ? tA3 : 0.0f;
            const float c0 = rA * logf(1.0f - pp) + y0 * logf(pp) + tt;
            // group 1
            mu  = expf(dot1);
            num = mu * mu * sqB;
            den = v1 * mu * smB + num;
            pp  = num / den;
            yi  = (int)y1;
            tt  = (yi == 1) ? tB1 : (yi == 2) ? tB2 : (yi == 3) ? tB3 : 0.0f;
            const float c1 = rB * logf(1.0f - pp) + y1 * logf(pp) + tt;
            accl += (double)c0 + (double)c1;
        }
    }

    sred[tid] = accl;
    __syncthreads();
    for (int s = 128; s > 0; s >>= 1) {
        if (tid < s) sred[tid] += sred[tid + s];
        __syncthreads();
    }
    if (tid == 0) {
        unsafeAtomicAdd(acc, sred[0]);
    }
}

// ---------------------------------------------------------------------------
// Kernel 3: finalize — negate and cast to f32 output.
// ---------------------------------------------------------------------------
__global__ void fin_kernel(const double* __restrict__ acc, float* __restrict__ out) {
    if (threadIdx.x == 0 && blockIdx.x == 0) out[0] = -(float)acc[0];
}

extern "C" void kernel_launch(void* const* d_in, const int* in_sizes, int n_in,
                              void* d_out, int out_size, void* d_ws, size_t ws_size,
                              hipStream_t stream) {
    const float* csb     = (const float*)d_in[0];
    const float* mod0    = (const float*)d_in[1];
    const float* mod1    = (const float*)d_in[2];
    const float* f0      = (const float*)d_in[3];
    const float* f1      = (const float*)d_in[4];
    const float* spatial = (const float*)d_in[5];
    const float* wm      = (const float*)d_in[6];
    const float* over    = (const float*)d_in[7];
    float*  out = (float*)d_out;
    double* acc = (double*)d_ws;
    float*  sc  = (float*)((char*)d_ws + 16);

    prep_kernel<<<1, 256, 0, stream>>>(mod0, mod1, wm, over, acc, sc);
    main_kernel<<<2048, 256, 0, stream>>>(csb, f0, f1, spatial, sc, acc);
    fin_kernel<<<1, 64, 0, stream>>>(acc, out);
}